// Round 6
// baseline (24.919 us; speedup 1.0000x reference)
//
#include <hip/hip_runtime.h>
#include <hip/hip_bf16.h>

#define S_IMG    128
#define KTOP     16
#define RAD2     (0.02f*0.02f)
#define INV_R2   (1.0f/RAD2)
#define RADF     0.02f
#define ZNEARF   1.0f
#define FOCALF   1.7320508075688772f   // 1/tan(30 deg)
#define TPI      16                    // tiles per image axis (128/8)
#define NTILE    (TPI*TPI)             // 256 tiles per image
#define CAP      160                   // bin capacity (expected worst ~105)
#define KSENT    0xFFFFFFFFu

// ---------------- camera basis helper (PyTorch3D look_at) ----------------
__device__ __forceinline__ void cam_basis(const float* __restrict__ eye, int b,
    float& ex, float& ey, float& ez,
    float& xax, float& xaz, float& yax, float& yay, float& yaz,
    float& zax, float& zay, float& zaz)
{
    ex = eye[b*3+0]; ey = eye[b*3+1]; ez = eye[b*3+2];
    float zinv = 1.0f / sqrtf(ex*ex + ey*ey + ez*ez);
    zax = -ex*zinv; zay = -ey*zinv; zaz = -ez*zinv;
    float xinv = 1.0f / sqrtf(zaz*zaz + zax*zax);
    xax = zaz*xinv; xaz = -zax*xinv;          // x-axis y-component == 0
    yax = zay*xaz;
    yay = zaz*xax - zax*xaz;
    yaz = -zay*xax;
}

// ---------------- kernel A: project + bin into 8x8-pixel tiles ----------------
__global__ __launch_bounds__(256) void bin_points(
    const float* __restrict__ points, const float* __restrict__ eye,
    int N, int NP,
    int* __restrict__ cnt, float* __restrict__ binX,
    float* __restrict__ binY, unsigned* __restrict__ binK)
{
    const int gid = blockIdx.x * 256 + threadIdx.x;
    if (gid >= NP) return;
    const int b = gid / N;
    const int j = gid - b * N;

    float ex,ey,ez, xax,xaz, yax,yay,yaz, zax,zay,zaz;
    cam_basis(eye, b, ex,ey,ez, xax,xaz, yax,yay,yaz, zax,zay,zaz);

    const float wx = points[gid*3+0] - ex;
    const float wy = points[gid*3+1] - ey;
    const float wz = points[gid*3+2] - ez;
    const float cz = wx*zax + wy*zay + wz*zaz;
    if (cz <= ZNEARF) return;
    const float inv = FOCALF / cz;
    const float xn = (wx*xax + wz*xaz) * inv;
    const float yn = (wx*yax + wy*yay + wz*yaz) * inv;

    // pixel-col/row ranges the disc can touch: pxc(c)=1-(2c+1)/128, decreasing
    int c_lo = (int)ceilf (64.0f*(1.0f - xn - RADF) - 0.5f - 1e-4f);
    int c_hi = (int)floorf(64.0f*(1.0f - xn + RADF) - 0.5f + 1e-4f);
    int r_lo = (int)ceilf (64.0f*(1.0f - yn - RADF) - 0.5f - 1e-4f);
    int r_hi = (int)floorf(64.0f*(1.0f - yn + RADF) - 0.5f + 1e-4f);
    if (c_lo < 0) c_lo = 0;  if (c_hi > S_IMG-1) c_hi = S_IMG-1;
    if (r_lo < 0) r_lo = 0;  if (r_hi > S_IMG-1) r_hi = S_IMG-1;
    if (c_lo > c_hi || r_lo > r_hi) return;

    const unsigned key = (__float_as_uint(cz) & ~2047u) | (unsigned)j;
    const int tx0 = c_lo >> 3, tx1 = c_hi >> 3;
    const int ty0 = r_lo >> 3, ty1 = r_hi >> 3;
    for (int ty = ty0; ty <= ty1; ++ty)
        for (int tx = tx0; tx <= tx1; ++tx) {
            const int bin = b * NTILE + ty * TPI + tx;
            const int slot = atomicAdd(&cnt[bin], 1);
            if (slot < CAP) {
                binX[bin*CAP + slot] = xn;
                binY[bin*CAP + slot] = yn;
                binK[bin*CAP + slot] = key;
            }
        }
}

// ---------------- kernel B: per 8x8 tile, sort bin by z, composite ----------------
__global__ __launch_bounds__(64) void render_bin(
    const int* __restrict__ cnt, const float* __restrict__ binX,
    const float* __restrict__ binY, const unsigned* __restrict__ binK,
    const float* __restrict__ colors, float* __restrict__ out, int N)
{
    __shared__ __align__(16) unsigned s_key[CAP + 8];
    __shared__ __align__(16) float2   s_sxy[CAP + 4];
    __shared__ __align__(16) float4   s_scol[CAP + 4];

    const int tid = threadIdx.x;
    const int blk = blockIdx.x;
    const int b   = blk >> 8;            // NTILE == 256
    const int t   = blk & 255;
    const int ty  = t >> 4, tx = t & 15;

    int M = cnt[b*NTILE + t];
    if (M > CAP) M = CAP;
    const int base = (b*NTILE + t) * CAP;

    // load bin; each lane keeps its own candidates in registers (<=3)
    float xr0=0,yr0=0,xr1=0,yr1=0,xr2=0,yr2=0;
    unsigned kr0=0,kr1=0,kr2=0;
    int no = 0;
    for (int i = tid; i < M; i += 64) {
        float x = binX[base+i], y = binY[base+i];
        unsigned k = binK[base+i];
        s_key[i] = k;
        if      (no == 0) { xr0=x; yr0=y; kr0=k; }
        else if (no == 1) { xr1=x; yr1=y; kr1=k; }
        else              { xr2=x; yr2=y; kr2=k; }
        ++no;
    }
    if (tid < 8) s_key[M + tid] = KSENT;
    __syncthreads();

    // rank-sort by unique key; scatter (x,y) + gathered color to sorted slots
    const float* cols = colors + b*N*3;
    const uint4* k4 = reinterpret_cast<const uint4*>(s_key);
    const int nb = (M + 7) >> 3;
    #pragma unroll
    for (int u = 0; u < 3; ++u) {
        if (u < no) {
            const unsigned mk = (u==0) ? kr0 : (u==1) ? kr1 : kr2;
            const float    ux = (u==0) ? xr0 : (u==1) ? xr1 : xr2;
            const float    uy = (u==0) ? yr0 : (u==1) ? yr1 : yr2;
            int rank = 0;
            for (int q = 0; q < nb; ++q) {
                uint4 a  = k4[2*q];
                uint4 bb = k4[2*q+1];
                rank += (int)(a.x <mk) + (int)(a.y <mk) + (int)(a.z <mk) + (int)(a.w <mk)
                      + (int)(bb.x<mk) + (int)(bb.y<mk) + (int)(bb.z<mk) + (int)(bb.w<mk);
            }
            const int pi = (int)(mk & 2047u);
            s_sxy [rank] = make_float2(ux, uy);
            s_scol[rank] = make_float4(cols[3*pi+0], cols[3*pi+1], cols[3*pi+2], 0.0f);
        }
    }
    if (tid < 4) {
        s_sxy [M + tid] = make_float2(1.0e9f, 1.0e9f);
        s_scol[M + tid] = make_float4(0.f, 0.f, 0.f, 0.f);
    }
    __syncthreads();

    // scan z-sorted list, composite on the fly (4 candidates/iter), 1 px/lane
    const int row = ty*8 + (tid >> 3);
    const int col = tx*8 + (tid & 7);
    const float pxc = 1.0f - (2.0f*col + 1.0f) / S_IMG;
    const float pyc = 1.0f - (2.0f*row + 1.0f) / S_IMG;

    const float4* xy4 = reinterpret_cast<const float4*>(s_sxy);
    float T = 1.0f, r = 0.0f, g = 0.0f, bl = 0.0f;
    int hits = 0;
    for (int i = 0; i < M; i += 4) {
        float4 u   = xy4[(i >> 1) + 0];
        float4 v   = xy4[(i >> 1) + 1];
        float4 c0v = s_scol[i + 0];
        float4 c1v = s_scol[i + 1];
        float4 c2v = s_scol[i + 2];
        float4 c3v = s_scol[i + 3];
        float dx, dy, d2, a, w; bool h;

        dx = pxc - u.x; dy = pyc - u.y; d2 = dx*dx + dy*dy;
        h = (d2 < RAD2) && (hits < KTOP); hits += h ? 1 : 0;
        a = h ? 1.0f - d2 * INV_R2 : 0.0f;
        w = a * T; r += w*c0v.x; g += w*c0v.y; bl += w*c0v.z; T -= T*a;

        dx = pxc - u.z; dy = pyc - u.w; d2 = dx*dx + dy*dy;
        h = (d2 < RAD2) && (hits < KTOP); hits += h ? 1 : 0;
        a = h ? 1.0f - d2 * INV_R2 : 0.0f;
        w = a * T; r += w*c1v.x; g += w*c1v.y; bl += w*c1v.z; T -= T*a;

        dx = pxc - v.x; dy = pyc - v.y; d2 = dx*dx + dy*dy;
        h = (d2 < RAD2) && (hits < KTOP); hits += h ? 1 : 0;
        a = h ? 1.0f - d2 * INV_R2 : 0.0f;
        w = a * T; r += w*c2v.x; g += w*c2v.y; bl += w*c2v.z; T -= T*a;

        dx = pxc - v.z; dy = pyc - v.w; d2 = dx*dx + dy*dy;
        h = (d2 < RAD2) && (hits < KTOP); hits += h ? 1 : 0;
        a = h ? 1.0f - d2 * INV_R2 : 0.0f;
        w = a * T; r += w*c3v.x; g += w*c3v.y; bl += w*c3v.z; T -= T*a;
    }

    const int gpix = b * (S_IMG*S_IMG) + row * S_IMG + col;
    float* o = out + (size_t)gpix * 3;
    o[0] = r; o[1] = g; o[2] = bl;
}

// ---------------- fallback: R5 single-kernel path (if ws too small) ----------------
#define TH  8
#define TW  16
#define TPB (TH*TW)
#define FCAP 512
__global__ __launch_bounds__(TPB) void render_tile(
    const float* __restrict__ points, const float* __restrict__ eye,
    const float* __restrict__ colors, float* __restrict__ out, int N)
{
    __shared__ float s_cx[FCAP];
    __shared__ float s_cy[FCAP];
    __shared__ __align__(16) unsigned s_key[FCAP + 8];
    __shared__ __align__(16) float2   s_sxy[FCAP + 4];
    __shared__ __align__(16) float4   s_scol[FCAP + 4];
    __shared__ int s_cnt;

    const int tid = threadIdx.x;
    const int blk = blockIdx.x;
    const int b   = blk >> 7;
    const int t   = blk & 127;
    const int tr  = t >> 3, tc = t & 7;
    const int r0  = tr * TH, c0 = tc * TW;

    float ex,ey,ez, xax,xaz, yax,yay,yaz, zax,zay,zaz;
    cam_basis(eye, b, ex,ey,ez, xax,xaz, yax,yay,yaz, zax,zay,zaz);

    const float cx = 1.0f - (float)(2*c0 + TW) / S_IMG;
    const float cy = 1.0f - (float)(2*r0 + TH) / S_IMG;
    const float hx = (float)(TW - 1) / S_IMG + RADF + 1e-6f;
    const float hy = (float)(TH - 1) / S_IMG + RADF + 1e-6f;

    if (tid == 0) s_cnt = 0;
    __syncthreads();

    const float* pts = points + b*N*3;
    #pragma unroll 4
    for (int j = tid; j < N; j += TPB) {
        float wx = pts[3*j+0] - ex;
        float wy = pts[3*j+1] - ey;
        float wz = pts[3*j+2] - ez;
        float cz = wx*zax + wy*zay + wz*zaz;
        if (cz > ZNEARF) {
            float inv = FOCALF / cz;
            float xn = (wx*xax + wz*xaz)*inv;
            float yn = (wx*yax + wy*yay + wz*yaz)*inv;
            if (fabsf(xn - cx) <= hx && fabsf(yn - cy) <= hy) {
                int slot = atomicAdd(&s_cnt, 1);
                if (slot < FCAP) {
                    s_cx[slot] = xn; s_cy[slot] = yn;
                    s_key[slot] = (__float_as_uint(cz) & ~2047u) | (unsigned)j;
                }
            }
        }
    }
    __syncthreads();
    int M = s_cnt; if (M > FCAP) M = FCAP;
    if (tid < 8) s_key[M + tid] = KSENT;
    if (tid < 4) {
        s_sxy [M + tid] = make_float2(1.0e9f, 1.0e9f);
        s_scol[M + tid] = make_float4(0.f, 0.f, 0.f, 0.f);
    }
    __syncthreads();

    const float* cols = colors + b*N*3;
    const uint4* k4 = reinterpret_cast<const uint4*>(s_key);
    const int nb = (M + 7) >> 3;
    for (int o = tid; o < M; o += TPB) {
        unsigned mk = s_key[o];
        int rank = 0;
        for (int q = 0; q < nb; ++q) {
            uint4 a = k4[2*q], bb = k4[2*q+1];
            rank += (int)(a.x <mk)+(int)(a.y <mk)+(int)(a.z <mk)+(int)(a.w <mk)
                  + (int)(bb.x<mk)+(int)(bb.y<mk)+(int)(bb.z<mk)+(int)(bb.w<mk);
        }
        int pi = (int)(mk & 2047u);
        s_sxy [rank] = make_float2(s_cx[o], s_cy[o]);
        s_scol[rank] = make_float4(cols[3*pi+0], cols[3*pi+1], cols[3*pi+2], 0.0f);
    }
    __syncthreads();

    const int row = r0 + (tid >> 4), col = c0 + (tid & 15);
    const float pxc = 1.0f - (2.0f*col + 1.0f) / S_IMG;
    const float pyc = 1.0f - (2.0f*row + 1.0f) / S_IMG;
    const float4* xy4 = reinterpret_cast<const float4*>(s_sxy);
    float T = 1.0f, r = 0.0f, g = 0.0f, bl = 0.0f;
    int hits = 0;
    for (int i = 0; i < M; i += 4) {
        float4 u = xy4[(i>>1)+0], v = xy4[(i>>1)+1];
        float4 c0v = s_scol[i+0], c1v = s_scol[i+1], c2v = s_scol[i+2], c3v = s_scol[i+3];
        float dx, dy, d2, a, w; bool h;
        dx=pxc-u.x; dy=pyc-u.y; d2=dx*dx+dy*dy; h=(d2<RAD2)&&(hits<KTOP); hits+=h?1:0;
        a=h?1.0f-d2*INV_R2:0.0f; w=a*T; r+=w*c0v.x; g+=w*c0v.y; bl+=w*c0v.z; T-=T*a;
        dx=pxc-u.z; dy=pyc-u.w; d2=dx*dx+dy*dy; h=(d2<RAD2)&&(hits<KTOP); hits+=h?1:0;
        a=h?1.0f-d2*INV_R2:0.0f; w=a*T; r+=w*c1v.x; g+=w*c1v.y; bl+=w*c1v.z; T-=T*a;
        dx=pxc-v.x; dy=pyc-v.y; d2=dx*dx+dy*dy; h=(d2<RAD2)&&(hits<KTOP); hits+=h?1:0;
        a=h?1.0f-d2*INV_R2:0.0f; w=a*T; r+=w*c2v.x; g+=w*c2v.y; bl+=w*c2v.z; T-=T*a;
        dx=pxc-v.z; dy=pyc-v.w; d2=dx*dx+dy*dy; h=(d2<RAD2)&&(hits<KTOP); hits+=h?1:0;
        a=h?1.0f-d2*INV_R2:0.0f; w=a*T; r+=w*c3v.x; g+=w*c3v.y; bl+=w*c3v.z; T-=T*a;
    }
    const int gpix = b*(S_IMG*S_IMG) + row*S_IMG + col;
    float* o = out + (size_t)gpix * 3;
    o[0] = r; o[1] = g; o[2] = bl;
}

extern "C" void kernel_launch(void* const* d_in, const int* in_sizes, int n_in,
                              void* d_out, int out_size, void* d_ws, size_t ws_size,
                              hipStream_t stream)
{
    const float* points = (const float*)d_in[0];
    const float* eye    = (const float*)d_in[1];
    const float* colors = (const float*)d_in[2];
    float* out = (float*)d_out;

    const int B = in_sizes[1] / 3;              // eye is [B,3]
    const int N = in_sizes[0] / (3 * B);        // points is [B,N,3]

    const size_t nbins = (size_t)B * NTILE;
    const size_t cntB  = nbins * sizeof(int);
    const size_t arrB  = nbins * CAP * 4;
    const size_t need  = cntB + 3 * arrB;

    if (ws_size >= need && N <= 2048) {
        int*      cnt  = (int*)d_ws;
        float*    binX = (float*)((char*)d_ws + cntB);
        float*    binY = (float*)((char*)d_ws + cntB + arrB);
        unsigned* binK = (unsigned*)((char*)d_ws + cntB + 2*arrB);

        hipMemsetAsync(cnt, 0, cntB, stream);
        const int NP = B * N;
        bin_points<<<(NP + 255) / 256, 256, 0, stream>>>(points, eye, N, NP,
                                                         cnt, binX, binY, binK);
        render_bin<<<B * NTILE, 64, 0, stream>>>(cnt, binX, binY, binK,
                                                 colors, out, N);
    } else {
        render_tile<<<B * 128, TPB, 0, stream>>>(points, eye, colors, out, N);
    }
}

// Round 7
// 22.441 us; speedup vs baseline: 1.1104x; 1.1104x over previous
//
#include <hip/hip_runtime.h>
#include <hip/hip_bf16.h>

#define S_IMG    128
#define KTOP     16
#define RAD2     (0.02f*0.02f)
#define INV_R2   (1.0f/RAD2)
#define RADF     0.02f
#define ZNEARF   1.0f
#define FOCALF   1.7320508075688772f   // 1/tan(30 deg)
#define TPI      16                    // 8x8-pixel tiles, 16 per axis
#define NTILE    (TPI*TPI)             // 256 tiles per image
#define TPB      64                    // one wave per block, 1 px/lane
#define CAP      256                   // worst central tile ~120 expected
#define KSENT    0xFFFFFFFFu

__global__ __launch_bounds__(TPB) void render_tile8(
    const float* __restrict__ points,
    const float* __restrict__ eye,
    const float* __restrict__ colors,
    float* __restrict__ out,
    int N)
{
    __shared__ float s_cx[CAP];
    __shared__ float s_cy[CAP];
    __shared__ __align__(16) unsigned s_key[CAP + 8];   // (z bits & ~2047) | idx
    __shared__ __align__(16) float2   s_sxy [CAP + 8];  // z-sorted (x,y) + sentinels
    __shared__ __align__(16) float4   s_scol[CAP + 8];  // z-sorted (r,g,b,-) + zeros
    __shared__ int s_cnt;

    const int tid = threadIdx.x;
    const int blk = blockIdx.x;
    const int b   = blk >> 8;                 // NTILE == 256
    const int t   = blk & 255;
    const int ty  = t >> 4, tx = t & 15;

    // ---- camera basis (PyTorch3D look_at: at=origin, up=+y; R cols = x,y,z) ----
    const float ex = eye[b*3+0], ey = eye[b*3+1], ez = eye[b*3+2];
    const float zinv = 1.0f / sqrtf(ex*ex + ey*ey + ez*ez);
    const float zax = -ex*zinv, zay = -ey*zinv, zaz = -ez*zinv;
    const float xinv = 1.0f / sqrtf(zaz*zaz + zax*zax);
    const float xax = zaz*xinv, xaz = -zax*xinv;       // x-axis y-component == 0
    const float yax = zay*xaz;
    const float yay = zaz*xax - zax*xaz;
    const float yaz = -zay*xax;

    // ---- tile bbox in NDC (pixel centers) + radius pad ----
    const float cx = 1.0f - (float)(2*(tx*8) + 8) / S_IMG;
    const float cy = 1.0f - (float)(2*(ty*8) + 8) / S_IMG;
    const float hx = 7.0f / S_IMG + RADF + 1e-6f;
    const float hy = 7.0f / S_IMG + RADF + 1e-6f;

    if (tid == 0) s_cnt = 0;
    __syncthreads();

    // ---- phase 1: project + tile-cull -> compact unordered candidate list ----
    const float* pts = points + b*N*3;
    #pragma unroll 4
    for (int j = tid; j < N; j += TPB) {
        float wx = pts[3*j+0] - ex;
        float wy = pts[3*j+1] - ey;
        float wz = pts[3*j+2] - ez;
        float cz = wx*zax + wy*zay + wz*zaz;
        if (cz > ZNEARF) {
            float inv = FOCALF / cz;
            float xn = (wx*xax + wz*xaz) * inv;
            float yn = (wx*yax + wy*yay + wz*yaz) * inv;
            if (fabsf(xn - cx) <= hx && fabsf(yn - cy) <= hy) {
                int slot = atomicAdd(&s_cnt, 1);
                if (slot < CAP) {
                    s_cx [slot] = xn;
                    s_cy [slot] = yn;
                    s_key[slot] = (__float_as_uint(cz) & ~2047u) | (unsigned)j;
                }
            }
        }
    }
    __syncthreads();
    int M = s_cnt; if (M > CAP) M = CAP;

    // ---- sentinel pads: keys never-smaller, xy never-hit, colors zero ----
    if (tid < 8) {
        s_key [M + tid] = KSENT;
        s_sxy [M + tid] = make_float2(1.0e9f, 1.0e9f);
        s_scol[M + tid] = make_float4(0.f, 0.f, 0.f, 0.f);
    }
    __syncthreads();

    // ---- phase 2: rank-sort by unique key; gather colors into sorted slots ----
    const float* cols = colors + b*N*3;
    const uint4* k4 = reinterpret_cast<const uint4*>(s_key);
    const int nb = (M + 7) >> 3;
    for (int o = tid; o < M; o += TPB) {
        const unsigned mk = s_key[o];
        const float ux = s_cx[o], uy = s_cy[o];
        int rank = 0;
        for (int q = 0; q < nb; ++q) {                 // 2x b128 broadcast reads
            uint4 a  = k4[2*q];
            uint4 bb = k4[2*q+1];
            rank += (int)(a.x <mk) + (int)(a.y <mk) + (int)(a.z <mk) + (int)(a.w <mk)
                  + (int)(bb.x<mk) + (int)(bb.y<mk) + (int)(bb.z<mk) + (int)(bb.w<mk);
        }
        const int pi = (int)(mk & 2047u);
        s_sxy [rank] = make_float2(ux, uy);
        s_scol[rank] = make_float4(cols[3*pi+0], cols[3*pi+1], cols[3*pi+2], 0.0f);
    }
    __syncthreads();

    // ---- phase 3: scan z-sorted list, software-pipelined (prefetch i+4) ----
    const int row = ty*8 + (tid >> 3);
    const int col = tx*8 + (tid & 7);
    const float pxc = 1.0f - (2.0f*col + 1.0f) / S_IMG;
    const float pyc = 1.0f - (2.0f*row + 1.0f) / S_IMG;

    const float4* xy4 = reinterpret_cast<const float4*>(s_sxy);
    float4 u  = xy4[0], v  = xy4[1];
    float4 ca = s_scol[0], cb = s_scol[1], cc = s_scol[2], cd = s_scol[3];

    float T = 1.0f, r = 0.0f, g = 0.0f, bl = 0.0f;
    int hits = 0;
    for (int i = 0; i < M; i += 4) {
        // prefetch next group while current is in registers
        float4 un = xy4[(i >> 1) + 2];
        float4 vn = xy4[(i >> 1) + 3];
        float4 na = s_scol[i + 4];
        float4 nb_ = s_scol[i + 5];
        float4 nc = s_scol[i + 6];
        float4 nd = s_scol[i + 7];

        float dx, dy, d2, a, w; bool h;

        dx = pxc - u.x; dy = pyc - u.y; d2 = dx*dx + dy*dy;
        h = (d2 < RAD2) && (hits < KTOP); hits += h ? 1 : 0;
        a = h ? 1.0f - d2 * INV_R2 : 0.0f;
        w = a * T; r += w*ca.x; g += w*ca.y; bl += w*ca.z; T -= T*a;

        dx = pxc - u.z; dy = pyc - u.w; d2 = dx*dx + dy*dy;
        h = (d2 < RAD2) && (hits < KTOP); hits += h ? 1 : 0;
        a = h ? 1.0f - d2 * INV_R2 : 0.0f;
        w = a * T; r += w*cb.x; g += w*cb.y; bl += w*cb.z; T -= T*a;

        dx = pxc - v.x; dy = pyc - v.y; d2 = dx*dx + dy*dy;
        h = (d2 < RAD2) && (hits < KTOP); hits += h ? 1 : 0;
        a = h ? 1.0f - d2 * INV_R2 : 0.0f;
        w = a * T; r += w*cc.x; g += w*cc.y; bl += w*cc.z; T -= T*a;

        dx = pxc - v.w == 0 ? pxc - v.z : pxc - v.z; dy = pyc - v.w; d2 = dx*dx + dy*dy;
        h = (d2 < RAD2) && (hits < KTOP); hits += h ? 1 : 0;
        a = h ? 1.0f - d2 * INV_R2 : 0.0f;
        w = a * T; r += w*cd.x; g += w*cd.y; bl += w*cd.z; T -= T*a;

        u = un; v = vn; ca = na; cb = nb_; cc = nc; cd = nd;
    }

    const int gpix = b * (S_IMG*S_IMG) + row * S_IMG + col;
    float* o = out + (size_t)gpix * 3;
    o[0] = r; o[1] = g; o[2] = bl;
}

extern "C" void kernel_launch(void* const* d_in, const int* in_sizes, int n_in,
                              void* d_out, int out_size, void* d_ws, size_t ws_size,
                              hipStream_t stream)
{
    const float* points = (const float*)d_in[0];
    const float* eye    = (const float*)d_in[1];
    const float* colors = (const float*)d_in[2];
    float* out = (float*)d_out;

    const int B = in_sizes[1] / 3;              // eye is [B,3]
    const int N = in_sizes[0] / (3 * B);        // points is [B,N,3] (N <= 2048)

    render_tile8<<<B * NTILE, TPB, 0, stream>>>(points, eye, colors, out, N);
}

// Round 8
// 15.025 us; speedup vs baseline: 1.6585x; 1.4935x over previous
//
#include <hip/hip_runtime.h>
#include <hip/hip_bf16.h>

#define S_IMG    128
#define KTOP     16
#define RAD2     (0.02f*0.02f)
#define INV_R2   (1.0f/RAD2)
#define RADF     0.02f
#define ZNEARF   1.0f
#define FOCALF   1.7320508075688772f   // 1/tan(30 deg)
#define TPI      16                    // 8x8-pixel tiles, 16 per axis
#define NTILE    (TPI*TPI)             // 256 tiles per image
#define TPB      256                   // 4 waves; 4 sub-lanes per pixel
#define CAP      256                   // worst central 8x8 tile ~150 expected
#define KSENT    0xFFFFFFFFu

__global__ __launch_bounds__(TPB) void render_tile8(
    const float* __restrict__ points,
    const float* __restrict__ eye,
    const float* __restrict__ colors,
    float* __restrict__ out,
    int N)
{
    __shared__ float s_cx[CAP];
    __shared__ float s_cy[CAP];
    __shared__ __align__(16) unsigned s_key[CAP + 8];    // (z bits & ~2047) | idx
    __shared__ __align__(16) float2   s_sxy [CAP + 16];  // z-sorted (x,y) + sentinels
    __shared__ __align__(16) float4   s_scol[CAP + 16];  // z-sorted (r,g,b,-) + zeros
    __shared__ int s_cnt;

    const int tid = threadIdx.x;
    const int blk = blockIdx.x;
    const int b   = blk >> 8;                  // NTILE == 256
    const int t   = blk & 255;
    const int ty  = t >> 4, tx = t & 15;

    // ---- camera basis (PyTorch3D look_at: at=origin, up=+y; R cols = x,y,z) ----
    const float ex = eye[b*3+0], ey = eye[b*3+1], ez = eye[b*3+2];
    const float zinv = 1.0f / sqrtf(ex*ex + ey*ey + ez*ez);
    const float zax = -ex*zinv, zay = -ey*zinv, zaz = -ez*zinv;
    const float xinv = 1.0f / sqrtf(zaz*zaz + zax*zax);
    const float xax = zaz*xinv, xaz = -zax*xinv;        // x-axis y-component == 0
    const float yax = zay*xaz;
    const float yay = zaz*xax - zax*xaz;
    const float yaz = -zay*xax;

    // ---- tile bbox in NDC (pixel centers) + radius pad ----
    const float cx = 1.0f - (float)(2*(tx*8) + 8) / S_IMG;
    const float cy = 1.0f - (float)(2*(ty*8) + 8) / S_IMG;
    const float hx = 7.0f / S_IMG + RADF + 1e-6f;
    const float hy = 7.0f / S_IMG + RADF + 1e-6f;

    if (tid == 0) s_cnt = 0;
    __syncthreads();

    // ---- phase 1: project + tile-cull (8 points/thread) ----
    const float* pts = points + b*N*3;
    #pragma unroll 4
    for (int j = tid; j < N; j += TPB) {
        float wx = pts[3*j+0] - ex;
        float wy = pts[3*j+1] - ey;
        float wz = pts[3*j+2] - ez;
        float cz = wx*zax + wy*zay + wz*zaz;
        if (cz > ZNEARF) {
            float inv = FOCALF / cz;
            float xn = (wx*xax + wz*xaz) * inv;
            float yn = (wx*yax + wy*yay + wz*yaz) * inv;
            if (fabsf(xn - cx) <= hx && fabsf(yn - cy) <= hy) {
                int slot = atomicAdd(&s_cnt, 1);
                if (slot < CAP) {
                    s_cx [slot] = xn;
                    s_cy [slot] = yn;
                    s_key[slot] = (__float_as_uint(cz) & ~2047u) | (unsigned)j;
                }
            }
        }
    }
    __syncthreads();
    int M = s_cnt; if (M > CAP) M = CAP;

    // ---- sentinel pads (phase 3 reads up to M+15; key scan up to 8-aligned) ----
    if (tid < 16) {
        if (tid < 8) s_key[M + tid] = KSENT;
        s_sxy [M + tid] = make_float2(1.0e9f, 1.0e9f);   // never hits
        s_scol[M + tid] = make_float4(0.f, 0.f, 0.f, 0.f);
    }
    __syncthreads();

    // ---- phase 2: rank-sort (1 candidate/thread); gather colors ----
    const float* cols = colors + b*N*3;
    if (tid < M) {
        const unsigned mk = s_key[tid];
        const float ux = s_cx[tid], uy = s_cy[tid];
        const uint4* k4 = reinterpret_cast<const uint4*>(s_key);
        const int nb = (M + 7) >> 3;
        int rank = 0;
        for (int q = 0; q < nb; ++q) {                   // broadcast b128 reads
            uint4 a  = k4[2*q];
            uint4 bb = k4[2*q+1];
            rank += (int)(a.x <mk) + (int)(a.y <mk) + (int)(a.z <mk) + (int)(a.w <mk)
                  + (int)(bb.x<mk) + (int)(bb.y<mk) + (int)(bb.z<mk) + (int)(bb.w<mk);
        }
        const int pi = (int)(mk & 2047u);
        s_sxy [rank] = make_float2(ux, uy);
        s_scol[rank] = make_float4(cols[3*pi+0], cols[3*pi+1], cols[3*pi+2], 0.0f);
    }
    __syncthreads();

    // ---- phase 3: 4 sub-lanes/pixel scan z-contiguous segments, then merge ----
    const int sub = tid & 3;                   // subs are adjacent lanes
    const int p   = tid >> 2;                  // pixel within tile (0..63)
    const int row = ty*8 + (p >> 3);
    const int col = tx*8 + (p & 7);
    const float pxc = 1.0f - (2.0f*col + 1.0f) / S_IMG;
    const float pyc = 1.0f - (2.0f*row + 1.0f) / S_IMG;

    const int L = 4 * ((M + 15) >> 4);         // per-sub segment (multiple of 4)
    const int base = sub * L;                  // max read index 4L-1 <= M+15

    const float4* xy4 = reinterpret_cast<const float4*>(s_sxy);
    float T = 1.0f, r = 0.0f, g = 0.0f, bl = 0.0f;
    int hits = 0;
    for (int i = 0; i < L; i += 4) {
        const int ii = base + i;
        float4 u   = xy4[(ii >> 1) + 0];
        float4 v   = xy4[(ii >> 1) + 1];
        float4 c0v = s_scol[ii + 0];
        float4 c1v = s_scol[ii + 1];
        float4 c2v = s_scol[ii + 2];
        float4 c3v = s_scol[ii + 3];
        float dx, dy, d2, a, w; bool h;

        dx = pxc - u.x; dy = pyc - u.y; d2 = dx*dx + dy*dy;
        h = (d2 < RAD2); hits += h ? 1 : 0;
        a = h ? 1.0f - d2 * INV_R2 : 0.0f;
        w = a * T; r += w*c0v.x; g += w*c0v.y; bl += w*c0v.z; T -= T*a;

        dx = pxc - u.z; dy = pyc - u.w; d2 = dx*dx + dy*dy;
        h = (d2 < RAD2); hits += h ? 1 : 0;
        a = h ? 1.0f - d2 * INV_R2 : 0.0f;
        w = a * T; r += w*c1v.x; g += w*c1v.y; bl += w*c1v.z; T -= T*a;

        dx = pxc - v.x; dy = pyc - v.y; d2 = dx*dx + dy*dy;
        h = (d2 < RAD2); hits += h ? 1 : 0;
        a = h ? 1.0f - d2 * INV_R2 : 0.0f;
        w = a * T; r += w*c2v.x; g += w*c2v.y; bl += w*c2v.z; T -= T*a;

        dx = pxc - v.z; dy = pyc - v.w; d2 = dx*dx + dy*dy;
        h = (d2 < RAD2); hits += h ? 1 : 0;
        a = h ? 1.0f - d2 * INV_R2 : 0.0f;
        w = a * T; r += w*c3v.x; g += w*c3v.y; bl += w*c3v.z; T -= T*a;
    }

    // ordered over-compose across the 4 subs (associative, non-commutative)
    #pragma unroll
    for (int mk2 = 1; mk2 <= 2; mk2 <<= 1) {
        float pr = __shfl_xor(r,  mk2, 64);
        float pg = __shfl_xor(g,  mk2, 64);
        float pb = __shfl_xor(bl, mk2, 64);
        float pT = __shfl_xor(T,  mk2, 64);
        int   ph = __shfl_xor(hits, mk2, 64);
        const bool lower = (sub & mk2) == 0;   // my segment precedes partner's
        r  = lower ? r  + T*pr : pr + pT*r;
        g  = lower ? g  + T*pg : pg + pT*g;
        bl = lower ? bl + T*pb : pb + pT*bl;
        T  = lower ? T*pT      : pT*T;
        hits += ph;
    }

    if (sub == 0) {
        if (hits > KTOP) {                     // exact K-cap fallback (≈ never)
            T = 1.0f; r = 0.0f; g = 0.0f; bl = 0.0f;
            int hh = 0;
            for (int i = 0; i < M && hh < KTOP; ++i) {
                float2 xy = s_sxy[i];
                float dx = pxc - xy.x, dy = pyc - xy.y;
                float d2 = dx*dx + dy*dy;
                if (d2 < RAD2) {
                    float4 cc = s_scol[i];
                    float a = 1.0f - d2 * INV_R2;
                    float w = a * T;
                    r += w*cc.x; g += w*cc.y; bl += w*cc.z;
                    T -= T*a; ++hh;
                }
            }
        }
        const int gpix = b * (S_IMG*S_IMG) + row * S_IMG + col;
        float* o = out + (size_t)gpix * 3;
        o[0] = r; o[1] = g; o[2] = bl;
    }
}

extern "C" void kernel_launch(void* const* d_in, const int* in_sizes, int n_in,
                              void* d_out, int out_size, void* d_ws, size_t ws_size,
                              hipStream_t stream)
{
    const float* points = (const float*)d_in[0];
    const float* eye    = (const float*)d_in[1];
    const float* colors = (const float*)d_in[2];
    float* out = (float*)d_out;

    const int B = in_sizes[1] / 3;              // eye is [B,3]
    const int N = in_sizes[0] / (3 * B);        // points is [B,N,3] (N <= 2048)

    render_tile8<<<B * NTILE, TPB, 0, stream>>>(points, eye, colors, out, N);
}